// Round 13
// baseline (58.933 us; speedup 1.0000x reference)
//
#include <hip/hip_runtime.h>

constexpr int Bn = 1024;
constexpr int Dn = 64;
constexpr int Cn = 100000;
constexpr int Kn = 5;
constexpr float LOG2E = 1.44269504088896f;
constexpr float LN2   = 0.69314718055994531f;

typedef float f32x4  __attribute__((ext_vector_type(4)));
typedef short bf16x8 __attribute__((ext_vector_type(8)));

__device__ __forceinline__ unsigned short f32_to_bf16(float f) {
  union { float f; unsigned int u; } v; v.f = f;
  unsigned int r = v.u + 0x7FFFu + ((v.u >> 16) & 1u);  // RNE
  return (unsigned short)(r >> 16);
}
__device__ __forceinline__ float bf16_to_f32(unsigned short u) {
  union { unsigned int i; float f; } v; v.i = ((unsigned int)u) << 16; return v.f;
}

// global -> LDS direct copy, 16B per lane. LDS dest is WAVE-UNIFORM base +
// lane*16 (HW semantics); global src is per-lane.
__device__ __forceinline__ void gl2lds16(const void* g, void* l) {
  __builtin_amdgcn_global_load_lds(
      (const __attribute__((address_space(1))) void*)g,
      (__attribute__((address_space(3))) void*)l, 16, 0, 0);
}

// ===================== MAIN PATH (r13) =====================
// r12 loop skeleton (4 LDS bufs, 2-chunk epochs, 13 barriers). r13 change:
// staging via global_load_lds width=16 from a PRE-CONVERTED, PRE-SWIZZLED
// bf16 Wt (built by prep). Deletes from the loop: 8 f32->bf16 conversions +
// 8 ds_write_b16 per thread-chunk (8x-duplicated across a split's blocks).
// Swizzle: octet o of class c stored at position o^(c&7) -> gemm's
// ds_read_b128 at swizzled offsets loads all 32 banks uniformly.
constexpr int SPLITS = 125;
constexpr int CPS    = Cn / SPLITS;   // 800
constexpr int NCH    = CPS / 32;      // 25 chunks of 32 classes
constexpr int SGRPS  = 8;             // 128 samples per block, 32 per wave
constexpr int GRID   = SPLITS * SGRPS; // 1000
constexpr int NBLK_W = (Cn + 63) / 64; // 1563 transpose tiles

// Prep: W[64][C] f32 -> Wt_swz[c][64] bf16, octet-XOR swizzled; zero out.
// Proven coalesced LDS-tile transpose (r1/r5); only the octet positions of
// the two 16B stores change (permutation within each 128B class row).
__global__ __launch_bounds__(256) void prep_kernel(
    const float* __restrict__ W, unsigned short* __restrict__ Wt,
    float* __restrict__ out)
{
  __shared__ unsigned short tile[64][71];   // [d][c]; odd pad
  const int tid = threadIdx.x;
  const int b   = blockIdx.x;
  if (b == 0 && tid == 0) *out = 0.f;   // replaces hipMemsetAsync dispatch

  const int c0   = b * 64;
  const int cIdx = tid & 63, dIdx = tid >> 6;
#pragma unroll
  for (int k = 0; k < 16; ++k) {
    const int d = dIdx * 16 + k;
    const int c = c0 + cIdx;
    const float v = (c < Cn) ? W[(size_t)d * Cn + c] : 0.f;
    tile[d][cIdx] = f32_to_bf16(v);
  }
  __syncthreads();
  const int cl = tid >> 2, dq = tid & 3;
  if (c0 + cl < Cn) {
    bf16x8 o0, o1;
#pragma unroll
    for (int k = 0; k < 8; ++k) o0[k] = (short)tile[dq * 16 + k][cl];
#pragma unroll
    for (int k = 0; k < 8; ++k) o1[k] = (short)tile[dq * 16 + 8 + k][cl];
    // c0 is a multiple of 64 -> (c & 7) == (cl & 7).
    const int swz = cl & 7;
    unsigned short* rowp = Wt + (size_t)(c0 + cl) * 64;
    *reinterpret_cast<bf16x8*>(rowp + ((2 * dq)     ^ swz) * 8) = o0;
    *reinterpret_cast<bf16x8*>(rowp + ((2 * dq + 1) ^ swz) * 8) = o1;
  }
}

__global__ __launch_bounds__(256) void gemm_gl_kernel(
    const float* __restrict__ x, const unsigned short* __restrict__ Wt,
    const float* __restrict__ bias, float* __restrict__ P)
{
  __shared__ unsigned short wl[4][32 * 64];   // 4 bufs x 4KB, LINEAR (gl2lds)

  const int b   = blockIdx.x;
  const int tid = threadIdx.x;

  // Bijective chunked XCD map (nwg=1000 = 8*125): a split's 8 sample-group
  // blocks land on one XCD -> its Wt slice is HBM-fetched once, L2-shared.
  const int xcd = b & 7, bs = b >> 3;
  const int wgid  = xcd * 125 + bs;
  const int split = wgid >> 3, sgrp = wgid & 7;

  const int lane = tid & 63, wid = tid >> 6;
  const int lr = lane & 15, lg = lane >> 4;
  const int sbase = sgrp * 128 + wid * 32;
  const int cb0   = split * CPS;

  // ---- A-frags: 32 samples/wave, f32 x -> bf16(x*LOG2E) in registers.
  bf16x8 a[2][2];
#pragma unroll
  for (int t = 0; t < 2; ++t) {
    const float* xp = x + (size_t)(sbase + t * 16 + lr) * 64 + lg * 8;
    const float4 v0 = *reinterpret_cast<const float4*>(xp);
    const float4 v1 = *reinterpret_cast<const float4*>(xp + 4);
    const float4 v2 = *reinterpret_cast<const float4*>(xp + 32);
    const float4 v3 = *reinterpret_cast<const float4*>(xp + 36);
    bf16x8 a0, a1;
    a0[0] = (short)f32_to_bf16(v0.x * LOG2E);
    a0[1] = (short)f32_to_bf16(v0.y * LOG2E);
    a0[2] = (short)f32_to_bf16(v0.z * LOG2E);
    a0[3] = (short)f32_to_bf16(v0.w * LOG2E);
    a0[4] = (short)f32_to_bf16(v1.x * LOG2E);
    a0[5] = (short)f32_to_bf16(v1.y * LOG2E);
    a0[6] = (short)f32_to_bf16(v1.z * LOG2E);
    a0[7] = (short)f32_to_bf16(v1.w * LOG2E);
    a1[0] = (short)f32_to_bf16(v2.x * LOG2E);
    a1[1] = (short)f32_to_bf16(v2.y * LOG2E);
    a1[2] = (short)f32_to_bf16(v2.z * LOG2E);
    a1[3] = (short)f32_to_bf16(v2.w * LOG2E);
    a1[4] = (short)f32_to_bf16(v3.x * LOG2E);
    a1[5] = (short)f32_to_bf16(v3.y * LOG2E);
    a1[6] = (short)f32_to_bf16(v3.z * LOG2E);
    a1[7] = (short)f32_to_bf16(v3.w * LOG2E);
    a[t][0] = a0;
    a[t][1] = a1;
  }

  // Staging: one 16B unit per thread per chunk, linear copy.
  // Wave wid covers bytes [wid*1KB, wid*1KB+1KB) of the 4KB chunk tile.
  const unsigned short* gsrc0 = Wt + (size_t)cb0 * 64 + tid * 8;  // per-lane
  // Swizzled read offsets (c&7 == lr&7 for rows lr and 16+lr: cb%32==0).
  const int ro0 = lr * 64, ro1 = (16 + lr) * 64;
  const int s0 = ((lg ^ (lr & 7)) << 3);
  const int s1 = (((4 + lg) ^ (lr & 7)) << 3);

  // ---- Prologue: issue chunks 0,1 into bufs 0,1.
  gl2lds16(gsrc0,            &wl[0][wid * 512]);
  gl2lds16(gsrc0 + 32 * 64,  &wl[1][wid * 512]);
  __syncthreads();   // drains vmcnt -> bufs 0,1 landed

  float esum[2][4];
#pragma unroll
  for (int t = 0; t < 2; ++t)
#pragma unroll
    for (int j = 0; j < 4; ++j) esum[t][j] = 0.f;

  // ---- Main loop: 2-chunk epochs, 1 barrier/epoch (13 total).
#pragma unroll 1
  for (int ch = 0; ch < NCH; ch += 2) {
    if (ch + 2 < NCH)
      gl2lds16(gsrc0 + (size_t)(ch + 2) * 32 * 64, &wl[(ch + 2) & 3][wid * 512]);
    if (ch + 3 < NCH)
      gl2lds16(gsrc0 + (size_t)(ch + 3) * 32 * 64, &wl[(ch + 3) & 3][wid * 512]);

#pragma unroll
    for (int e = 0; e < 2; ++e) {
      const int c = ch + e;
      if (c < NCH) {
        const unsigned short* wb = wl[c & 3];
        const int cb = cb0 + c * 32;
        const float bb0 = bias[cb + lr] * LOG2E;
        const float bb1 = bias[cb + 16 + lr] * LOG2E;
        const bf16x8 b00 = *reinterpret_cast<const bf16x8*>(&wb[ro0 + s0]);
        const bf16x8 b01 = *reinterpret_cast<const bf16x8*>(&wb[ro0 + s1]);
        const bf16x8 b10 = *reinterpret_cast<const bf16x8*>(&wb[ro1 + s0]);
        const bf16x8 b11 = *reinterpret_cast<const bf16x8*>(&wb[ro1 + s1]);
#pragma unroll
        for (int t = 0; t < 2; ++t) {
          f32x4 acc0 = {bb0, bb0, bb0, bb0};
          f32x4 acc1 = {bb1, bb1, bb1, bb1};
          acc0 = __builtin_amdgcn_mfma_f32_16x16x32_bf16(a[t][0], b00, acc0, 0, 0, 0);
          acc1 = __builtin_amdgcn_mfma_f32_16x16x32_bf16(a[t][0], b10, acc1, 0, 0, 0);
          acc0 = __builtin_amdgcn_mfma_f32_16x16x32_bf16(a[t][1], b01, acc0, 0, 0, 0);
          acc1 = __builtin_amdgcn_mfma_f32_16x16x32_bf16(a[t][1], b11, acc1, 0, 0, 0);
#pragma unroll
          for (int j = 0; j < 4; ++j) {
            const float e0 = __builtin_amdgcn_exp2f(acc0[j]);
            const float e1 = __builtin_amdgcn_exp2f(acc1[j]);
            esum[t][j] += e0 + e1;
          }
        }
      }
    }
    __syncthreads();   // drains vmcnt (epoch's loads landed) + syncs bufs
  }

  // ---- Reduce over the 16 lr-lanes (classes), once; P[sample][split].
  float red[2][4];
#pragma unroll
  for (int t = 0; t < 2; ++t)
#pragma unroll
    for (int j = 0; j < 4; ++j) {
      float v = esum[t][j];
      v += __shfl_xor(v, 1, 64);
      v += __shfl_xor(v, 2, 64);
      v += __shfl_xor(v, 4, 64);
      v += __shfl_xor(v, 8, 64);
      red[t][j] = v;
    }
  if (lr == 0) {
#pragma unroll
    for (int t = 0; t < 2; ++t)
#pragma unroll
      for (int j = 0; j < 4; ++j)
        P[(size_t)(sbase + t * 16 + lg * 4 + j) * SPLITS + split] = red[t][j];
  }
}

// Loss: P reduce (coalesced) + positives recomputed from f32 W/x with the
// SAME bf16 rounding expressions as prep/gemm (log2 domain). Independent of
// Wt's swizzled layout.
__global__ __launch_bounds__(64) void loss3_kernel(
    const float* __restrict__ x, const int* __restrict__ labels,
    const float* __restrict__ W, const float* __restrict__ bias,
    const float* __restrict__ P, float* __restrict__ out)
{
  const int i = blockIdx.x, lane = threadIdx.x;
  float acc = P[(size_t)i * SPLITS + lane];
  if (lane + 64 < SPLITS) acc += P[(size_t)i * SPLITS + lane + 64];
#pragma unroll
  for (int off = 32; off > 0; off >>= 1) acc += __shfl_xor(acc, off, 64);
  const float Si = acc;

  const float xv = bf16_to_f32(f32_to_bf16(x[i * Dn + lane] * LOG2E));  // == A-frag
  float l2[Kn];
#pragma unroll
  for (int p = 0; p < Kn; ++p) {
    const int c = labels[i * Kn + p];
    const float wv = bf16_to_f32(f32_to_bf16(W[(size_t)lane * Cn + c]));  // == Wt
    float v = xv * wv;
#pragma unroll
    for (int off = 32; off > 0; off >>= 1) v += __shfl_xor(v, off, 64);
    l2[p] = v + bias[c] * LOG2E;    // logit * LOG2E
  }
  if (lane == 0) {
    float Psum = 0.f;
#pragma unroll
    for (int p = 0; p < Kn; ++p) Psum += __builtin_amdgcn_exp2f(l2[p]);
    const float neg = Si - Psum;
    float lsum = 0.f;
#pragma unroll
    for (int p = 0; p < Kn; ++p)
      lsum += __logf(__builtin_amdgcn_exp2f(l2[p]) + neg) - l2[p] * LN2;
    atomicAdd(out, lsum * (1.0f / (float)(Bn * Kn)));
  }
}

// ===================== OLD (round-2) FALLBACK PATH =====================
constexpr int NB  = 128;
constexpr int NPB = (Cn + NB - 1) / NB;
constexpr int NPBpad = 784;

__global__ __launch_bounds__(256) void cvt_x_kernel(
    const float* __restrict__ x, unsigned short* __restrict__ xb)
{
  const int i = (blockIdx.x * 256 + threadIdx.x) * 4;
  const float4 v = *reinterpret_cast<const float4*>(x + i);
  ushort4 o;
  o.x = f32_to_bf16(v.x); o.y = f32_to_bf16(v.y);
  o.z = f32_to_bf16(v.z); o.w = f32_to_bf16(v.w);
  *reinterpret_cast<ushort4*>(xb + i) = o;
}

__global__ __launch_bounds__(256) void expsum_mfma_kernel(
    const unsigned short* __restrict__ xb, const float* __restrict__ W,
    const float* __restrict__ bias, float* __restrict__ P,
    float* __restrict__ S, int use_partials)
{
  __shared__ float S_lds[4][Bn];
  const int tid  = threadIdx.x;
  const int lane = tid & 63, wid = tid >> 6;
  const int lg = lane >> 4, lr = lane & 15;
  const int cbase = blockIdx.x * NB + wid * 32;

  for (int i = tid; i < 4 * Bn; i += 256) (&S_lds[0][0])[i] = 0.f;

  bf16x8 bfrag[2][2];
  float  bval[2];
#pragma unroll
  for (int t = 0; t < 2; ++t) {
    const int c  = cbase + t * 16 + lr;
    const bool ok = (c < Cn);
    bval[t] = ok ? bias[c] * LOG2E : -1e38f;
#pragma unroll
    for (int h = 0; h < 2; ++h) {
      bf16x8 bf;
#pragma unroll
      for (int j = 0; j < 8; ++j) {
        const int d = h * 32 + lg * 8 + j;
        const float w = ok ? W[(size_t)d * Cn + c] : 0.f;
        bf[j] = (short)f32_to_bf16(w);
      }
      bfrag[t][h] = bf;
    }
  }
  __syncthreads();

#pragma unroll 1
  for (int ch = 0; ch < Bn / 16; ++ch) {
    const int s = ch * 16 + lr;
    const bf16x8 a0 = *reinterpret_cast<const bf16x8*>(xb + (size_t)s * Dn + lg * 8);
    const bf16x8 a1 = *reinterpret_cast<const bf16x8*>(xb + (size_t)s * Dn + 32 + lg * 8);
    f32x4 acc0 = {0.f, 0.f, 0.f, 0.f};
    f32x4 acc1 = {0.f, 0.f, 0.f, 0.f};
    acc0 = __builtin_amdgcn_mfma_f32_16x16x32_bf16(a0, bfrag[0][0], acc0, 0, 0, 0);
    acc1 = __builtin_amdgcn_mfma_f32_16x16x32_bf16(a0, bfrag[1][0], acc1, 0, 0, 0);
    acc0 = __builtin_amdgcn_mfma_f32_16x16x32_bf16(a1, bfrag[0][1], acc0, 0, 0, 0);
    acc1 = __builtin_amdgcn_mfma_f32_16x16x32_bf16(a1, bfrag[1][1], acc1, 0, 0, 0);

    float v[4];
#pragma unroll
    for (int j = 0; j < 4; ++j) {
      const float e0 = __builtin_amdgcn_exp2f(fmaf(acc0[j], LOG2E, bval[0]));
      const float e1 = __builtin_amdgcn_exp2f(fmaf(acc1[j], LOG2E, bval[1]));
      v[j] = e0 + e1;
    }
#pragma unroll
    for (int j = 0; j < 4; ++j) {
      v[j] += __shfl_xor(v[j], 1, 64);
      v[j] += __shfl_xor(v[j], 2, 64);
      v[j] += __shfl_xor(v[j], 4, 64);
      v[j] += __shfl_xor(v[j], 8, 64);
    }
    if (lr == 0) {
#pragma unroll
      for (int j = 0; j < 4; ++j)
        S_lds[wid][ch * 16 + lg * 4 + j] += v[j];
    }
  }
  __syncthreads();

  if (use_partials) {
    for (int s2 = tid; s2 < Bn; s2 += 256) {
      const float v = S_lds[0][s2] + S_lds[1][s2] + S_lds[2][s2] + S_lds[3][s2];
      P[(size_t)s2 * NPBpad + blockIdx.x] = v;
    }
  } else {
    for (int s2 = tid; s2 < Bn; s2 += 256) {
      const float v = S_lds[0][s2] + S_lds[1][s2] + S_lds[2][s2] + S_lds[3][s2];
      atomicAdd(&S[s2], v);
    }
  }
}

__global__ __launch_bounds__(64) void loss_kernel(
    const float* __restrict__ x, const int* __restrict__ labels,
    const float* __restrict__ W, const float* __restrict__ bias,
    const float* __restrict__ P, const float* __restrict__ S,
    float* __restrict__ out, int use_partials)
{
  const int i    = blockIdx.x;
  const int lane = threadIdx.x;

  float Si;
  if (use_partials) {
    float acc = 0.f;
    for (int j = lane; j < NPB; j += 64) acc += P[(size_t)i * NPBpad + j];
#pragma unroll
    for (int off = 32; off > 0; off >>= 1) acc += __shfl_xor(acc, off, 64);
    Si = acc;
  } else {
    Si = S[i];
  }

  const float xv = x[i * Dn + lane];
  float l[Kn];
#pragma unroll
  for (int p = 0; p < Kn; ++p) {
    const int c = labels[i * Kn + p];
    float v = xv * W[(size_t)lane * Cn + c];
#pragma unroll
    for (int off = 32; off > 0; off >>= 1) v += __shfl_xor(v, off, 64);
    l[p] = v + bias[c];
  }

  if (lane == 0) {
    float Psum = 0.f;
#pragma unroll
    for (int p = 0; p < Kn; ++p) Psum += __expf(l[p]);
    const float neg = Si - Psum;
    float lsum = 0.f;
#pragma unroll
    for (int p = 0; p < Kn; ++p)
      lsum += __logf(__expf(l[p]) + neg) - l[p];
    atomicAdd(out, lsum * (1.0f / (float)(Bn * Kn)));
  }
}

// ===================== launch =====================
extern "C" void kernel_launch(void* const* d_in, const int* in_sizes, int n_in,
                              void* d_out, int out_size, void* d_ws, size_t ws_size,
                              hipStream_t stream) {
  const float* x      = (const float*)d_in[0];
  const int*   labels = (const int*)d_in[1];
  const float* W      = (const float*)d_in[2];
  const float* bias   = (const float*)d_in[3];
  float*       out    = (float*)d_out;
  char*        ws     = (char*)d_ws;

  // Main-path ws layout: P[512000) | Wt[12.8M)
  const size_t off_P  = 0;
  const size_t off_Wt = (size_t)SPLITS * Bn * 4;             // 512000
  const size_t need_new = off_Wt + (size_t)Cn * Dn * 2;      // 13312000

  if (ws_size >= need_new) {
    float*          P  = (float*)(ws + off_P);
    unsigned short* Wt = (unsigned short*)(ws + off_Wt);
    prep_kernel<<<NBLK_W, 256, 0, stream>>>(W, Wt, out);
    gemm_gl_kernel<<<GRID, 256, 0, stream>>>(x, Wt, bias, P);
    loss3_kernel<<<Bn, 64, 0, stream>>>(x, labels, W, bias, P, out);
    return;
  }

  // Fallback: round-2 path.
  hipMemsetAsync(out, 0, sizeof(float), stream);
  float*          Sg = (float*)ws;
  unsigned short* xb = (unsigned short*)(ws + 4096);
  float*          Pp = (float*)(ws + 4096 + (size_t)Bn * Dn * 2);
  const size_t need_old = 4096 + (size_t)Bn * Dn * 2 + (size_t)Bn * NPBpad * 4;
  const int use_partials = (ws_size >= need_old) ? 1 : 0;
  if (!use_partials) hipMemsetAsync(Sg, 0, Bn * sizeof(float), stream);

  cvt_x_kernel<<<(Bn * Dn) / (256 * 4), 256, 0, stream>>>(x, xb);
  expsum_mfma_kernel<<<NPB, 256, 0, stream>>>(xb, W, bias, Pp, Sg, use_partials);
  loss_kernel<<<Bn, 64, 0, stream>>>(x, labels, W, bias, Pp, Sg, out, use_partials);
}

// Round 14
// 52.558 us; speedup vs baseline: 1.1213x; 1.1213x over previous
//
#include <hip/hip_runtime.h>

constexpr int Bn = 1024;
constexpr int Dn = 64;
constexpr int Cn = 100000;
constexpr int Kn = 5;
constexpr float LOG2E = 1.44269504088896f;
constexpr float LN2   = 0.69314718055994531f;

typedef float f32x4  __attribute__((ext_vector_type(4)));
typedef short bf16x8 __attribute__((ext_vector_type(8)));

__device__ __forceinline__ unsigned short f32_to_bf16(float f) {
  union { float f; unsigned int u; } v; v.f = f;
  unsigned int r = v.u + 0x7FFFu + ((v.u >> 16) & 1u);  // RNE
  return (unsigned short)(r >> 16);
}
__device__ __forceinline__ float bf16_to_f32(unsigned short u) {
  union { unsigned int i; float f; } v; v.i = ((unsigned int)u) << 16; return v.f;
}

// ===================== FUSED MAIN PATH =====================
// r12 base (best total 52.6: conflict-free wt_off, 4 LDS bufs, 2-chunk
// epochs, r6 loop order). r14 change: bias staged to LDS ONCE per block
// (x LOG2E pre-applied). Removes the 2 per-chunk GLOBAL bias loads that sat
// directly upstream of the MFMA C-init (a ~200cyc serial bubble per chunk
// that prefetching never covered; unroll-1 blocked hoisting). Everything
// else byte-identical to r12.
constexpr int SPLITS = 125;
constexpr int CPS    = Cn / SPLITS;   // 800
constexpr int NCH    = CPS / 32;      // 25 chunks of 32 classes
constexpr int SGRPS  = 8;             // 128 samples per block, 32 per wave
constexpr int GRID   = SPLITS * SGRPS; // 1000
constexpr int WROW   = 120;           // LDS row stride (shorts); conflict-free

// addr(c,d) = c*120 + 8*(c>>2) + d  (shorts); row span 119 < 120, no overlap.
__device__ __forceinline__ int wt_off(int c, int d) {
  return c * WROW + ((c >> 2) << 3) + d;
}

// One 32-class chunk: bias C-init from LDS (log2 domain, pre-scaled),
// 4 ds_read_b128, 8 MFMA, 16 exp2. Same math as r6/r11/r12 (absmax 0.0).
__device__ __forceinline__ void computeChunk32(
    const unsigned short* __restrict__ wbuf, const float* __restrict__ bl,
    int cbl, int lr, int lg, const bf16x8 (&a)[2][2], float (&esum)[2][4])
{
  const float bb0 = bl[cbl + lr];        // bias*LOG2E, staged in LDS
  const float bb1 = bl[cbl + 16 + lr];
  const bf16x8 b00 = *reinterpret_cast<const bf16x8*>(&wbuf[wt_off(lr, lg * 8)]);
  const bf16x8 b01 = *reinterpret_cast<const bf16x8*>(&wbuf[wt_off(lr, 32 + lg * 8)]);
  const bf16x8 b10 = *reinterpret_cast<const bf16x8*>(&wbuf[wt_off(16 + lr, lg * 8)]);
  const bf16x8 b11 = *reinterpret_cast<const bf16x8*>(&wbuf[wt_off(16 + lr, 32 + lg * 8)]);
#pragma unroll
  for (int t = 0; t < 2; ++t) {
    f32x4 acc0 = {bb0, bb0, bb0, bb0};
    f32x4 acc1 = {bb1, bb1, bb1, bb1};
    acc0 = __builtin_amdgcn_mfma_f32_16x16x32_bf16(a[t][0], b00, acc0, 0, 0, 0);
    acc1 = __builtin_amdgcn_mfma_f32_16x16x32_bf16(a[t][0], b10, acc1, 0, 0, 0);
    acc0 = __builtin_amdgcn_mfma_f32_16x16x32_bf16(a[t][1], b01, acc0, 0, 0, 0);
    acc1 = __builtin_amdgcn_mfma_f32_16x16x32_bf16(a[t][1], b11, acc1, 0, 0, 0);
#pragma unroll
    for (int j = 0; j < 4; ++j) {
      const float e0 = __builtin_amdgcn_exp2f(acc0[j]);
      const float e1 = __builtin_amdgcn_exp2f(acc1[j]);
      esum[t][j] += e0 + e1;
    }
  }
}

__global__ __launch_bounds__(256) void fused_gemm_kernel(
    const float* __restrict__ x, const float* __restrict__ W,
    const float* __restrict__ bias, float* __restrict__ P,
    float* __restrict__ out)
{
  __shared__ unsigned short wt[4][32 * WROW];   // 30.7 KB, 4-buffer rotation
  __shared__ float bias_lds[CPS];               // 3.2 KB, bias*LOG2E

  const int b   = blockIdx.x;
  const int tid = threadIdx.x;
  if (b == 0 && tid == 0) *out = 0.f;   // replaces memset dispatch

  // Bijective chunked XCD map (nwg=1000 = 8*125): a split's 8 sample-group
  // blocks land on one XCD -> its 204.8KB W slice is HBM-fetched once.
  const int xcd = b & 7, bs = b >> 3;
  const int wgid  = xcd * 125 + bs;
  const int split = wgid >> 3, sgrp = wgid & 7;

  const int lane = tid & 63, wid = tid >> 6;
  const int lr = lane & 15, lg = lane >> 4;
  const int sbase = sgrp * 128 + wid * 32;
  const int cb0   = split * CPS;

  // ---- Stage this split's bias slice (x LOG2E) into LDS, once.
  for (int i = tid; i < CPS; i += 256) bias_lds[i] = bias[cb0 + i] * LOG2E;

  // ---- A-frags: 32 samples/wave, f32 x -> bf16(x*LOG2E) in registers.
  bf16x8 a[2][2];
#pragma unroll
  for (int t = 0; t < 2; ++t) {
    const float* xp = x + (size_t)(sbase + t * 16 + lr) * 64 + lg * 8;
    const float4 v0 = *reinterpret_cast<const float4*>(xp);
    const float4 v1 = *reinterpret_cast<const float4*>(xp + 4);
    const float4 v2 = *reinterpret_cast<const float4*>(xp + 32);
    const float4 v3 = *reinterpret_cast<const float4*>(xp + 36);
    bf16x8 a0, a1;
    a0[0] = (short)f32_to_bf16(v0.x * LOG2E);
    a0[1] = (short)f32_to_bf16(v0.y * LOG2E);
    a0[2] = (short)f32_to_bf16(v0.z * LOG2E);
    a0[3] = (short)f32_to_bf16(v0.w * LOG2E);
    a0[4] = (short)f32_to_bf16(v1.x * LOG2E);
    a0[5] = (short)f32_to_bf16(v1.y * LOG2E);
    a0[6] = (short)f32_to_bf16(v1.z * LOG2E);
    a0[7] = (short)f32_to_bf16(v1.w * LOG2E);
    a1[0] = (short)f32_to_bf16(v2.x * LOG2E);
    a1[1] = (short)f32_to_bf16(v2.y * LOG2E);
    a1[2] = (short)f32_to_bf16(v2.z * LOG2E);
    a1[3] = (short)f32_to_bf16(v2.w * LOG2E);
    a1[4] = (short)f32_to_bf16(v3.x * LOG2E);
    a1[5] = (short)f32_to_bf16(v3.y * LOG2E);
    a1[6] = (short)f32_to_bf16(v3.z * LOG2E);
    a1[7] = (short)f32_to_bf16(v3.w * LOG2E);
    a[t][0] = a0;
    a[t][1] = a1;
  }

  // Staging roles (r6): thread t loads float4 of W rows sd and sd+32 at
  // classes [sc, sc+4). One inst = 8 rows x 128B contiguous (coalesced).
  const int sd = tid >> 3;          // 0..31
  const int sc = (tid & 7) * 4;     // 0..28
  const float* wrow0 = W + (size_t)sd * Cn;
  const float* wrow1 = W + (size_t)(sd + 32) * Cn;

  // ---- Prologue: stage chunks 0 and 1 into bufs 0 and 1.
#pragma unroll
  for (int c0 = 0; c0 < 2; ++c0) {
    const int cbn = cb0 + c0 * 32;
    const float4 v0 = *reinterpret_cast<const float4*>(wrow0 + cbn + sc);
    const float4 v1 = *reinterpret_cast<const float4*>(wrow1 + cbn + sc);
#pragma unroll
    for (int j = 0; j < 4; ++j) {
      wt[c0][wt_off(sc + j, sd)]      = f32_to_bf16(v0[j]);
      wt[c0][wt_off(sc + j, sd + 32)] = f32_to_bf16(v1[j]);
    }
  }
  __syncthreads();   // bias_lds + bufs 0,1 ready

  float esum[2][4];
#pragma unroll
  for (int t = 0; t < 2; ++t)
#pragma unroll
    for (int j = 0; j < 4; ++j) esum[t][j] = 0.f;

  // ---- Main loop: 2-chunk epochs, barrier per epoch (13 total).
#pragma unroll 1
  for (int ch = 0; ch < NCH; ch += 2) {
    float4 nA0, nA1, nB0, nB1;
    const bool m2 = (ch + 2 < NCH);
    const bool m3 = (ch + 3 < NCH);
    if (m2) {
      const int cbn = cb0 + (ch + 2) * 32;
      nA0 = *reinterpret_cast<const float4*>(wrow0 + cbn + sc);
      nA1 = *reinterpret_cast<const float4*>(wrow1 + cbn + sc);
    }
    if (m3) {
      const int cbn = cb0 + (ch + 3) * 32;
      nB0 = *reinterpret_cast<const float4*>(wrow0 + cbn + sc);
      nB1 = *reinterpret_cast<const float4*>(wrow1 + cbn + sc);
    }

    computeChunk32(wt[ch & 3], bias_lds, ch * 32, lr, lg, a, esum);
    if (ch + 1 < NCH)
      computeChunk32(wt[(ch + 1) & 3], bias_lds, (ch + 1) * 32, lr, lg, a, esum);

    if (m2) {
      unsigned short* dst = wt[(ch + 2) & 3];
#pragma unroll
      for (int j = 0; j < 4; ++j) {
        dst[wt_off(sc + j, sd)]      = f32_to_bf16(nA0[j]);
        dst[wt_off(sc + j, sd + 32)] = f32_to_bf16(nA1[j]);
      }
    }
    if (m3) {
      unsigned short* dst = wt[(ch + 3) & 3];
#pragma unroll
      for (int j = 0; j < 4; ++j) {
        dst[wt_off(sc + j, sd)]      = f32_to_bf16(nB0[j]);
        dst[wt_off(sc + j, sd + 32)] = f32_to_bf16(nB1[j]);
      }
    }
    __syncthreads();
  }

  // ---- Reduce over the 16 lr-lanes (classes), once; P[sample][split].
  float red[2][4];
#pragma unroll
  for (int t = 0; t < 2; ++t)
#pragma unroll
    for (int j = 0; j < 4; ++j) {
      float v = esum[t][j];
      v += __shfl_xor(v, 1, 64);
      v += __shfl_xor(v, 2, 64);
      v += __shfl_xor(v, 4, 64);
      v += __shfl_xor(v, 8, 64);
      red[t][j] = v;
    }
  if (lr == 0) {
#pragma unroll
    for (int t = 0; t < 2; ++t)
#pragma unroll
      for (int j = 0; j < 4; ++j)
        P[(size_t)(sbase + t * 16 + lg * 4 + j) * SPLITS + split] = red[t][j];
  }
}

// Loss: P reduce (coalesced) + positives recomputed from f32 W/x with the
// SAME bf16 rounding expressions as the gemm (log2 domain).
__global__ __launch_bounds__(64) void loss3_kernel(
    const float* __restrict__ x, const int* __restrict__ labels,
    const float* __restrict__ W, const float* __restrict__ bias,
    const float* __restrict__ P, float* __restrict__ out)
{
  const int i = blockIdx.x, lane = threadIdx.x;
  float acc = P[(size_t)i * SPLITS + lane];
  if (lane + 64 < SPLITS) acc += P[(size_t)i * SPLITS + lane + 64];
#pragma unroll
  for (int off = 32; off > 0; off >>= 1) acc += __shfl_xor(acc, off, 64);
  const float Si = acc;

  const float xv = bf16_to_f32(f32_to_bf16(x[i * Dn + lane] * LOG2E));  // == A-frag
  float l2[Kn];
#pragma unroll
  for (int p = 0; p < Kn; ++p) {
    const int c = labels[i * Kn + p];
    const float wv = bf16_to_f32(f32_to_bf16(W[(size_t)lane * Cn + c]));  // == staged W
    float v = xv * wv;
#pragma unroll
    for (int off = 32; off > 0; off >>= 1) v += __shfl_xor(v, off, 64);
    l2[p] = v + bias[c] * LOG2E;    // logit * LOG2E
  }
  if (lane == 0) {
    float Psum = 0.f;
#pragma unroll
    for (int p = 0; p < Kn; ++p) Psum += __builtin_amdgcn_exp2f(l2[p]);
    const float neg = Si - Psum;
    float lsum = 0.f;
#pragma unroll
    for (int p = 0; p < Kn; ++p)
      lsum += __logf(__builtin_amdgcn_exp2f(l2[p]) + neg) - l2[p] * LN2;
    atomicAdd(out, lsum * (1.0f / (float)(Bn * Kn)));
  }
}

// ===================== OLD (round-2) FALLBACK PATH =====================
constexpr int NB  = 128;
constexpr int NPB = (Cn + NB - 1) / NB;
constexpr int NPBpad = 784;

__global__ __launch_bounds__(256) void cvt_x_kernel(
    const float* __restrict__ x, unsigned short* __restrict__ xb)
{
  const int i = (blockIdx.x * 256 + threadIdx.x) * 4;
  const float4 v = *reinterpret_cast<const float4*>(x + i);
  ushort4 o;
  o.x = f32_to_bf16(v.x); o.y = f32_to_bf16(v.y);
  o.z = f32_to_bf16(v.z); o.w = f32_to_bf16(v.w);
  *reinterpret_cast<ushort4*>(xb + i) = o;
}

__global__ __launch_bounds__(256) void expsum_mfma_kernel(
    const unsigned short* __restrict__ xb, const float* __restrict__ W,
    const float* __restrict__ bias, float* __restrict__ P,
    float* __restrict__ S, int use_partials)
{
  __shared__ float S_lds[4][Bn];
  const int tid  = threadIdx.x;
  const int lane = tid & 63, wid = tid >> 6;
  const int lg = lane >> 4, lr = lane & 15;
  const int cbase = blockIdx.x * NB + wid * 32;

  for (int i = tid; i < 4 * Bn; i += 256) (&S_lds[0][0])[i] = 0.f;

  bf16x8 bfrag[2][2];
  float  bval[2];
#pragma unroll
  for (int t = 0; t < 2; ++t) {
    const int c  = cbase + t * 16 + lr;
    const bool ok = (c < Cn);
    bval[t] = ok ? bias[c] * LOG2E : -1e38f;
#pragma unroll
    for (int h = 0; h < 2; ++h) {
      bf16x8 bf;
#pragma unroll
      for (int j = 0; j < 8; ++j) {
        const int d = h * 32 + lg * 8 + j;
        const float w = ok ? W[(size_t)d * Cn + c] : 0.f;
        bf[j] = (short)f32_to_bf16(w);
      }
      bfrag[t][h] = bf;
    }
  }
  __syncthreads();

#pragma unroll 1
  for (int ch = 0; ch < Bn / 16; ++ch) {
    const int s = ch * 16 + lr;
    const bf16x8 a0 = *reinterpret_cast<const bf16x8*>(xb + (size_t)s * Dn + lg * 8);
    const bf16x8 a1 = *reinterpret_cast<const bf16x8*>(xb + (size_t)s * Dn + 32 + lg * 8);
    f32x4 acc0 = {0.f, 0.f, 0.f, 0.f};
    f32x4 acc1 = {0.f, 0.f, 0.f, 0.f};
    acc0 = __builtin_amdgcn_mfma_f32_16x16x32_bf16(a0, bfrag[0][0], acc0, 0, 0, 0);
    acc1 = __builtin_amdgcn_mfma_f32_16x16x32_bf16(a0, bfrag[1][0], acc1, 0, 0, 0);
    acc0 = __builtin_amdgcn_mfma_f32_16x16x32_bf16(a1, bfrag[0][1], acc0, 0, 0, 0);
    acc1 = __builtin_amdgcn_mfma_f32_16x16x32_bf16(a1, bfrag[1][1], acc1, 0, 0, 0);

    float v[4];
#pragma unroll
    for (int j = 0; j < 4; ++j) {
      const float e0 = __builtin_amdgcn_exp2f(fmaf(acc0[j], LOG2E, bval[0]));
      const float e1 = __builtin_amdgcn_exp2f(fmaf(acc1[j], LOG2E, bval[1]));
      v[j] = e0 + e1;
    }
#pragma unroll
    for (int j = 0; j < 4; ++j) {
      v[j] += __shfl_xor(v[j], 1, 64);
      v[j] += __shfl_xor(v[j], 2, 64);
      v[j] += __shfl_xor(v[j], 4, 64);
      v[j] += __shfl_xor(v[j], 8, 64);
    }
    if (lr == 0) {
#pragma unroll
      for (int j = 0; j < 4; ++j)
        S_lds[wid][ch * 16 + lg * 4 + j] += v[j];
    }
  }
  __syncthreads();

  if (use_partials) {
    for (int s2 = tid; s2 < Bn; s2 += 256) {
      const float v = S_lds[0][s2] + S_lds[1][s2] + S_lds[2][s2] + S_lds[3][s2];
      P[(size_t)s2 * NPBpad + blockIdx.x] = v;
    }
  } else {
    for (int s2 = tid; s2 < Bn; s2 += 256) {
      const float v = S_lds[0][s2] + S_lds[1][s2] + S_lds[2][s2] + S_lds[3][s2];
      atomicAdd(&S[s2], v);
    }
  }
}

__global__ __launch_bounds__(64) void loss_kernel(
    const float* __restrict__ x, const int* __restrict__ labels,
    const float* __restrict__ W, const float* __restrict__ bias,
    const float* __restrict__ P, const float* __restrict__ S,
    float* __restrict__ out, int use_partials)
{
  const int i    = blockIdx.x;
  const int lane = threadIdx.x;

  float Si;
  if (use_partials) {
    float acc = 0.f;
    for (int j = lane; j < NPB; j += 64) acc += P[(size_t)i * NPBpad + j];
#pragma unroll
    for (int off = 32; off > 0; off >>= 1) acc += __shfl_xor(acc, off, 64);
    Si = acc;
  } else {
    Si = S[i];
  }

  const float xv = x[i * Dn + lane];
  float l[Kn];
#pragma unroll
  for (int p = 0; p < Kn; ++p) {
    const int c = labels[i * Kn + p];
    float v = xv * W[(size_t)lane * Cn + c];
#pragma unroll
    for (int off = 32; off > 0; off >>= 1) v += __shfl_xor(v, off, 64);
    l[p] = v + bias[c];
  }

  if (lane == 0) {
    float Psum = 0.f;
#pragma unroll
    for (int p = 0; p < Kn; ++p) Psum += __expf(l[p]);
    const float neg = Si - Psum;
    float lsum = 0.f;
#pragma unroll
    for (int p = 0; p < Kn; ++p)
      lsum += __logf(__expf(l[p]) + neg) - l[p];
    atomicAdd(out, lsum * (1.0f / (float)(Bn * Kn)));
  }
}

// ===================== launch =====================
extern "C" void kernel_launch(void* const* d_in, const int* in_sizes, int n_in,
                              void* d_out, int out_size, void* d_ws, size_t ws_size,
                              hipStream_t stream) {
  const float* x      = (const float*)d_in[0];
  const int*   labels = (const int*)d_in[1];
  const float* W      = (const float*)d_in[2];
  const float* bias   = (const float*)d_in[3];
  float*       out    = (float*)d_out;
  char*        ws     = (char*)d_ws;

  // Fused-path ws layout: P[512000) only.
  const size_t need_new = (size_t)SPLITS * Bn * 4;   // 512000

  if (ws_size >= need_new) {
    float* P = (float*)ws;
    fused_gemm_kernel<<<GRID, 256, 0, stream>>>(x, W, bias, P, out);
    loss3_kernel<<<Bn, 64, 0, stream>>>(x, labels, W, bias, P, out);
    return;
  }

  // Fallback: round-2 path.
  hipMemsetAsync(out, 0, sizeof(float), stream);
  float*          Sg = (float*)ws;
  unsigned short* xb = (unsigned short*)(ws + 4096);
  float*          Pp = (float*)(ws + 4096 + (size_t)Bn * Dn * 2);
  const size_t need_old = 4096 + (size_t)Bn * Dn * 2 + (size_t)Bn * NPBpad * 4;
  const int use_partials = (ws_size >= need_old) ? 1 : 0;
  if (!use_partials) hipMemsetAsync(Sg, 0, Bn * sizeof(float), stream);

  cvt_x_kernel<<<(Bn * Dn) / (256 * 4), 256, 0, stream>>>(x, xb);
  expsum_mfma_kernel<<<NPB, 256, 0, stream>>>(xb, W, bias, Pp, Sg, use_partials);
  loss_kernel<<<Bn, 64, 0, stream>>>(x, labels, W, bias, Pp, Sg, out, use_partials);
}